// Round 1
// baseline (240.075 us; speedup 1.0000x reference)
//
#include <hip/hip_runtime.h>
#include <math.h>

#define NEGV (-1e30f)
#define CTC_T 512
#define CTC_C 256
#define CTC_L 128
#define BLANKC (CTC_C - 1)
#define PFD 8  // prefetch depth (steps ahead)

#if __has_builtin(__builtin_amdgcn_exp2f)
__device__ __forceinline__ float fexp2(float x) { return __builtin_amdgcn_exp2f(x); }
#else
__device__ __forceinline__ float fexp2(float x) { return exp2f(x); }
#endif
#if __has_builtin(__builtin_amdgcn_logf)
__device__ __forceinline__ float flog2(float x) { return __builtin_amdgcn_logf(x); }
#else
__device__ __forceinline__ float flog2(float x) { return log2f(x); }
#endif

// log2-domain logaddexp: log2(2^a + 2^b)
__device__ __forceinline__ float lae2(float a, float b) {
    float m = fmaxf(a, b);
    float n = fminf(a, b);
    return m + flog2(1.0f + fexp2(n - m));  // n-m <= 0; exp underflows to 0 for NEG
}
// log2(2^a + 2^b + 2^c) — max contributes exactly 1.0, only 2 exps needed
__device__ __forceinline__ float lae3(float a, float b, float c) {
    float mx = fmaxf(fmaxf(a, b), c);
    float me = fmaxf(fminf(a, b), fminf(fmaxf(a, b), c)); // median
    float mn = fminf(fminf(a, b), c);
    return mx + flog2(1.0f + fexp2(me - mx) + fexp2(mn - mx));
}

// One wave per batch element. Thread k owns states 4k..4k+3; lane 63 also owns s=256.
// Even states are blanks (no skip path). Odd state 4k+1 -> label 2k; 4k+3 -> label 2k+1.
// alpha kept in log2 domain; emit = log2(p + 1e-7) - log2(1 + C*1e-7).
__global__ __launch_bounds__(64) void ctc_fwd_kernel(
    const int* __restrict__ y_true,    // [B, L]
    const float* __restrict__ y_pred,  // [B, T, C]
    const int* __restrict__ in_len,    // [B]
    const int* __restrict__ lab_len,   // [B]
    float* __restrict__ out)           // [B]
{
    const int b = blockIdx.x;
    const int k = threadIdx.x;  // 0..63

    const float* __restrict__ ybase = y_pred + (size_t)b * CTC_T * CTC_C;
    const int* __restrict__ yt = y_true + (size_t)b * CTC_L;

    const int l0 = yt[2 * k];
    const int l1 = yt[2 * k + 1];
    const int lm1 = __shfl_up(l1, 1);  // yt[2k-1] for k>0
    const bool skip1 = (k > 0) && (l0 != lm1) && (l0 != BLANKC);  // s=4k+1 vs s-2
    const bool skip3 = (l1 != l0) && (l1 != BLANKC);              // s=4k+3 vs s-2

    const float LSE2 = flog2(1.0f + (float)CTC_C * 1e-7f);

    // t = 0 init: alpha0[0] = emit(0, blank), alpha0[1] = emit(0, lab[0])
    float eb0 = flog2(ybase[BLANKC] + 1e-7f) - LSE2;
    float e00 = flog2(ybase[l0] + 1e-7f) - LSE2;
    float a0 = (k == 0) ? eb0 : NEGV;
    float a1 = (k == 0) ? e00 : NEGV;
    float a2 = NEGV, a3 = NEGV, a4 = NEGV;

    int inl = in_len[b];
    if (inl > CTC_T) inl = CTC_T;
    const int nsteps = inl - 1;  // update steps t = 1..nsteps

    // Register prefetch ring: raw y_pred values, log applied at consume time.
    float pb[PFD], p0[PFD], p1[PFD];
#pragma unroll
    for (int i = 1; i <= PFD; ++i) {
        if (i <= nsteps) {
            const float* row = ybase + (size_t)i * CTC_C;
            pb[i - 1] = row[BLANKC];
            p0[i - 1] = row[l0];
            p1[i - 1] = row[l1];
        }
    }

#define CTC_STEP(slot, tt)                                                  \
    {                                                                       \
        float _eb = flog2(pb[slot] + 1e-7f) - LSE2;                         \
        float _e0 = flog2(p0[slot] + 1e-7f) - LSE2;                         \
        float _e1 = flog2(p1[slot] + 1e-7f) - LSE2;                         \
        float _pm3 = __shfl_up(a3, 1); /* alpha[4k-1] from thread k-1 */    \
        if (k == 0) _pm3 = NEGV;                                            \
        float _n0 = lae2(a0, _pm3) + _eb;                                   \
        float _n1 = lae3(a1, a0, skip1 ? _pm3 : NEGV) + _e0;                \
        float _n2 = lae2(a2, a1) + _eb;                                     \
        float _n3 = lae3(a3, a2, skip3 ? a1 : NEGV) + _e1;                  \
        if (k == 63) a4 = lae2(a4, a3) + _eb; /* s=256, uses OLD a3 */      \
        a0 = _n0; a1 = _n1; a2 = _n2; a3 = _n3;                             \
        int _tp = (tt) + PFD;                                               \
        if (_tp <= nsteps) {                                                \
            const float* _row = ybase + (size_t)_tp * CTC_C;                \
            pb[slot] = _row[BLANKC];                                        \
            p0[slot] = _row[l0];                                            \
            p1[slot] = _row[l1];                                            \
        }                                                                   \
    }

    for (int t = 1; t <= nsteps; t += PFD) {
        CTC_STEP(0, t)
        if (t + 1 <= nsteps) CTC_STEP(1, t + 1)
        if (t + 2 <= nsteps) CTC_STEP(2, t + 2)
        if (t + 3 <= nsteps) CTC_STEP(3, t + 3)
        if (t + 4 <= nsteps) CTC_STEP(4, t + 4)
        if (t + 5 <= nsteps) CTC_STEP(5, t + 5)
        if (t + 6 <= nsteps) CTC_STEP(6, t + 6)
        if (t + 7 <= nsteps) CTC_STEP(7, t + 7)
    }
#undef CTC_STEP

    // Gather final alphas, compute loss on lane 0.
    __shared__ float sh[2 * CTC_L + 1];
    sh[4 * k + 0] = a0;
    sh[4 * k + 1] = a1;
    sh[4 * k + 2] = a2;
    sh[4 * k + 3] = a3;
    if (k == 63) sh[256] = a4;
    __syncthreads();
    if (k == 0) {
        int ll = lab_len[b];
        if (ll < 1) ll = 1;
        if (ll > CTC_L) ll = CTC_L;
        float ea = sh[2 * ll - 1];
        float eb = sh[2 * ll];
        // back to natural log: loss = -ln(2) * log2(2^ea + 2^eb)
        out[b] = -0.69314718055994530942f * lae2(ea, eb);
    }
}

extern "C" void kernel_launch(void* const* d_in, const int* in_sizes, int n_in,
                              void* d_out, int out_size, void* d_ws, size_t ws_size,
                              hipStream_t stream) {
    (void)n_in; (void)d_ws; (void)ws_size;
    const int* y_true = (const int*)d_in[0];
    const float* y_pred = (const float*)d_in[1];
    const int* in_len = (const int*)d_in[2];
    const int* lab_len = (const int*)d_in[3];
    float* out = (float*)d_out;
    const int B = in_sizes[2];  // input_length has B elements
    (void)out_size;
    ctc_fwd_kernel<<<B, 64, 0, stream>>>(y_true, y_pred, in_len, lab_len, out);
}

// Round 3
// 134.219 us; speedup vs baseline: 1.7887x; 1.7887x over previous
//
#include <hip/hip_runtime.h>
#include <math.h>

#define NEGV (-1e30f)
#define CTC_T 512
#define CTC_C 256
#define CTC_L 128
#define BLANKC (CTC_C - 1)
#define RING 16   // LDS ring slots (power of 2)
#define PFD 12    // prefetch depth (rows in flight); vmcnt(PFD-1) waits

#if __has_builtin(__builtin_amdgcn_exp2f)
__device__ __forceinline__ float fexp2(float x) { return __builtin_amdgcn_exp2f(x); }
#else
__device__ __forceinline__ float fexp2(float x) { return exp2f(x); }
#endif
#if __has_builtin(__builtin_amdgcn_logf)
__device__ __forceinline__ float flog2(float x) { return __builtin_amdgcn_logf(x); }
#else
__device__ __forceinline__ float flog2(float x) { return log2f(x); }
#endif

// log2-domain logaddexp: log2(2^a + 2^b)
__device__ __forceinline__ float lae2(float a, float b) {
    float m = fmaxf(a, b);
    float n = fminf(a, b);
    return m + flog2(1.0f + fexp2(n - m));  // n-m <= 0; underflows to 0 for NEG
}
// log2(2^a + 2^b + 2^c)
__device__ __forceinline__ float lae3(float a, float b, float c) {
    float mab = fmaxf(a, b);
    float nab = fminf(a, b);
    float mx = fmaxf(mab, c);
    float me = fmaxf(nab, fminf(mab, c));  // median
    float mn = fminf(nab, c);
    return mx + flog2(1.0f + fexp2(me - mx) + fexp2(mn - mx));
}

// One wave per batch element. Thread k owns states 4k..4k+3; lane 63 also owns
// s=256 (computed unconditionally on all lanes, only lane 63's is real).
// Even states = blanks (no skip path). State 4k+1 -> label 2k; 4k+3 -> label 2k+1.
// alpha kept in log2 domain WITHOUT the per-step log-softmax constant;
// corrected at the end by cnt*LSE2 (every surviving path has exactly cnt emits).
__global__ __launch_bounds__(64) void ctc_fwd_kernel(
    const int* __restrict__ y_true,    // [B, L]
    const float* __restrict__ y_pred,  // [B, T, C]
    const int* __restrict__ in_len,    // [B]
    const int* __restrict__ lab_len,   // [B]
    float* __restrict__ out)           // [B]
{
    __shared__ float ring[RING][CTC_C];   // 16 KB staging ring
    __shared__ float sh[2 * CTC_L + 1];

    const int b = blockIdx.x;
    const int k = threadIdx.x;  // 0..63

    const float* __restrict__ ybase = y_pred + (size_t)b * CTC_T * CTC_C;
    const int* __restrict__ yt = y_true + (size_t)b * CTC_L;

    const int l0 = yt[2 * k];
    const int l1 = yt[2 * k + 1];
    const int lm1 = __shfl_up(l1, 1);  // yt[2k-1] for k>0
    const bool skip1 = (k > 0) && (l0 != lm1) && (l0 != BLANKC);  // s=4k+1 skip
    const bool skip3 = (l1 != l0) && (l1 != BLANKC);              // s=4k+3 skip

    int inl = in_len[b];
    if (inl > CTC_T) inl = CTC_T;
    const int nsteps = inl - 1;  // update steps t = 1..nsteps (may be <= 0)

    // t = 0 init (plain global loads, one-time latency)
    float eb0 = flog2(ybase[BLANKC] + 1e-7f);
    float e00 = flog2(ybase[l0] + 1e-7f);
    float a0 = (k == 0) ? eb0 : NEGV;
    float a1 = (k == 0) ? e00 : NEGV;
    float a2 = NEGV, a3 = NEGV, a4 = NEGV;

    // ---- prologue: issue PFD row-loads into the LDS ring (1 KB each) ----
#pragma unroll
    for (int i = 1; i <= PFD; ++i) {
        int rp = (i > CTC_T - 1) ? (CTC_T - 1) : i;
        const float* src = ybase + (size_t)rp * CTC_C + (k << 2);
        __builtin_amdgcn_global_load_lds(
            (const __attribute__((address_space(1))) void*)src,
            (__attribute__((address_space(3))) void*)&ring[rp & (RING - 1)][0],
            16, 0, 0);
    }

    if (nsteps >= 1) {
        // wait for row 1, preload its 3 gather values into registers
        asm volatile("s_waitcnt vmcnt(" "11" ")" ::: "memory");
        float pb = ring[1][BLANKC];
        float p0 = ring[1][l0];
        float p1 = ring[1][l1];

#pragma unroll 2
        for (int t = 1; t <= nsteps; ++t) {
            // cross-lane value first (DS op, retires before the gather reads)
            float _pm3 = __shfl_up(a3, 1);  // alpha[4k-1] from lane k-1
            // issue prefetch of row t+PFD (keeps 12 loads in flight)
            int rp = t + PFD;
            if (rp > CTC_T - 1) rp = CTC_T - 1;
            const float* src = ybase + (size_t)rp * CTC_C + (k << 2);
            __builtin_amdgcn_global_load_lds(
                (const __attribute__((address_space(1))) void*)src,
                (__attribute__((address_space(3))) void*)&ring[rp & (RING - 1)][0],
                16, 0, 0);
            // counted wait: row t+1 has landed (never drain to 0)
            asm volatile("s_waitcnt vmcnt(" "11" ")" ::: "memory");
            int rn = t + 1;
            if (rn > CTC_T - 1) rn = CTC_T - 1;
            const float* rowl = &ring[rn & (RING - 1)][0];
            float pbn = rowl[BLANKC];   // broadcast (same addr all lanes)
            float p0n = rowl[l0];       // per-lane gather
            float p1n = rowl[l1];

            // ---- alpha update for step t (uses pb/p0/p1 loaded last iter) ----
            float _eb = flog2(pb + 1e-7f);
            float _e0 = flog2(p0 + 1e-7f);
            float _e1 = flog2(p1 + 1e-7f);
            if (k == 0) _pm3 = NEGV;
            float _n0 = lae2(a0, _pm3) + _eb;
            float _n1 = lae3(a1, a0, skip1 ? _pm3 : NEGV) + _e0;
            float _n2 = lae2(a2, a1) + _eb;
            float _n3 = lae3(a3, a2, skip3 ? a1 : NEGV) + _e1;
            a4 = lae2(a4, a3) + _eb;  // real only on lane 63 (s=256)
            a0 = _n0; a1 = _n1; a2 = _n2; a3 = _n3;
            pb = pbn; p0 = p0n; p1 = p1n;
        }
    }

    // gather final alphas, compute loss on lane 0
    sh[4 * k + 0] = a0;
    sh[4 * k + 1] = a1;
    sh[4 * k + 2] = a2;
    sh[4 * k + 3] = a3;
    if (k == 63) sh[256] = a4;
    __syncthreads();
    if (k == 0) {
        int ll = lab_len[b];
        if (ll < 1) ll = 1;
        if (ll > CTC_L) ll = CTC_L;
        float ea = sh[2 * ll - 1];
        float eb = sh[2 * ll];
        // every path has cnt = 1 + max(0, nsteps) emit terms; restore the
        // per-emit log-softmax constant here instead of inside the loop.
        int cnt = 1 + (nsteps > 0 ? nsteps : 0);
        const float LSE2 = flog2(1.0f + (float)CTC_C * 1e-7f);
        out[b] = -0.69314718055994530942f * (lae2(ea, eb) - (float)cnt * LSE2);
    }
}

extern "C" void kernel_launch(void* const* d_in, const int* in_sizes, int n_in,
                              void* d_out, int out_size, void* d_ws, size_t ws_size,
                              hipStream_t stream) {
    (void)n_in; (void)d_ws; (void)ws_size; (void)out_size;
    const int* y_true = (const int*)d_in[0];
    const float* y_pred = (const float*)d_in[1];
    const int* in_len = (const int*)d_in[2];
    const int* lab_len = (const int*)d_in[3];
    float* out = (float*)d_out;
    const int B = in_sizes[2];  // input_length has B elements
    ctc_fwd_kernel<<<B, 64, 0, stream>>>(y_true, y_pred, in_len, lab_len, out);
}